// Round 2
// baseline (243.669 us; speedup 1.0000x reference)
//
#include <hip/hip_runtime.h>
#include <hip/hip_cooperative_groups.h>
#include <math.h>

namespace cg = cooperative_groups;

// Problem constants (from reference)
constexpr int VOCAB = 100000;
constexpr int DIM   = 128;
constexpr int B     = 16384;
constexpr int K     = 10;
constexpr int BPB   = 8;            // batch elements per block per pass (256 thr = 8 x 32-lane groups)
constexpr int GRID  = 1024;         // 4 blocks/CU co-resident -> cooperative launch always fits
constexpr int CHUNK = GRID * BPB;   // 8192 elements per pass; 2 passes cover B=16384

// Single cooperative kernel:
//   phase 1: each block computes partial loss for 2 chunks of 8 batch elements
//            -> partial[blockIdx.x] (1024 floats in d_ws)
//   grid.sync()
//   phase 2: block 0 reduces the 1024 partials and writes out[0] = -total.
// No atomics, no zero-kernel, one dispatch.
__global__ __launch_bounds__(256, 4) void skipgram_fused_kernel(
    const int*   __restrict__ center_id,
    const int*   __restrict__ pos_id,
    const int*   __restrict__ neg_ids,
    const float* __restrict__ W_in,
    const float* __restrict__ W_out,
    float*       __restrict__ partial,
    float*       __restrict__ out)
{
    const int tid    = threadIdx.x;
    const int lane32 = tid & 31;   // dim-group index (0..31); 32 lanes x float4 = 128 = DIM
    const int sub    = tid >> 5;   // batch element within block (0..7)

    float acc = 0.f;               // per-(lane32==0) accumulated log-sigmoid sum

#pragma unroll
    for (int pass = 0; pass < 2; ++pass) {
        const int b = pass * CHUNK + blockIdx.x * BPB + sub;

        // Issue all 12 index loads up front -> one memory round-trip for addresses.
        const int cid = center_id[b];
        const int pid = pos_id[b];
        int nid[K];
#pragma unroll
        for (int k = 0; k < K; ++k) nid[k] = neg_ids[b * K + k];

        const float4 c = ((const float4*)(W_in  + (size_t)cid * DIM))[lane32];
        const float4 p = ((const float4*)(W_out + (size_t)pid * DIM))[lane32];

        // Sum the 10 negative rows first: neg contribution is
        // log_sigmoid(-dot(center, sum_k neg_k))  (sum over k happens before sigmoid)
        float4 ns = make_float4(0.f, 0.f, 0.f, 0.f);
#pragma unroll
        for (int k = 0; k < K; ++k) {
            const float4 n = ((const float4*)(W_out + (size_t)nid[k] * DIM))[lane32];
            ns.x += n.x; ns.y += n.y; ns.z += n.z; ns.w += n.w;
        }

        float pos_partial = c.x * p.x  + c.y * p.y  + c.z * p.z  + c.w * p.w;
        float neg_partial = c.x * ns.x + c.y * ns.y + c.z * ns.z + c.w * ns.w;

        // Reduce across the 32 lanes sharing this batch element.
        // xor masks <= 16 stay within each 32-lane half of the 64-lane wave.
#pragma unroll
        for (int m = 16; m >= 1; m >>= 1) {
            pos_partial += __shfl_xor(pos_partial, m, 64);
            neg_partial += __shfl_xor(neg_partial, m, 64);
        }

        if (lane32 == 0) {
            const float ps  = pos_partial;
            const float nsc = neg_partial;
            // stable log_sigmoid(x) = min(x,0) - log1p(exp(-|x|))
            const float lp = fminf(ps,   0.f) - log1pf(expf(-fabsf(ps)));
            const float ln = fminf(-nsc, 0.f) - log1pf(expf(-fabsf(nsc)));
            acc += lp + ln;
        }
    }

    // Block-level partial -> partial[blockIdx.x]
    __shared__ float blocksum[BPB];
    if (lane32 == 0) blocksum[sub] = acc;
    __syncthreads();
    if (tid == 0) {
        float s = 0.f;
#pragma unroll
        for (int i = 0; i < BPB; ++i) s += blocksum[i];
        partial[blockIdx.x] = s;
    }

    // Grid-wide barrier (device-scope fence included): all partials visible after.
    cg::this_grid().sync();

    // Final reduction by block 0: 1024 floats = 256 threads x float4.
    if (blockIdx.x == 0) {
        const float4 v = ((const float4*)partial)[tid];
        float s = v.x + v.y + v.z + v.w;
#pragma unroll
        for (int m = 32; m >= 1; m >>= 1) s += __shfl_xor(s, m, 64);

        __shared__ float wsum[4];
        if ((tid & 63) == 0) wsum[tid >> 6] = s;
        __syncthreads();
        if (tid == 0) out[0] = -(wsum[0] + wsum[1] + wsum[2] + wsum[3]);
    }
}

extern "C" void kernel_launch(void* const* d_in, const int* in_sizes, int n_in,
                              void* d_out, int out_size, void* d_ws, size_t ws_size,
                              hipStream_t stream) {
    const int*   center_id = (const int*)  d_in[0];
    const int*   pos_id    = (const int*)  d_in[1];
    const int*   neg_ids   = (const int*)  d_in[2];
    const float* W_in      = (const float*)d_in[3];
    const float* W_out     = (const float*)d_in[4];
    float*       out       = (float*)d_out;
    float*       partial   = (float*)d_ws;       // 1024 floats = 4 KB of workspace

    void* args[] = {
        (void*)&center_id, (void*)&pos_id, (void*)&neg_ids,
        (void*)&W_in, (void*)&W_out, (void*)&partial, (void*)&out
    };
    hipLaunchCooperativeKernel((const void*)skipgram_fused_kernel,
                               dim3(GRID), dim3(256), args, 0, stream);
}

// Round 3
// 123.362 us; speedup vs baseline: 1.9752x; 1.9752x over previous
//
#include <hip/hip_runtime.h>
#include <math.h>

// Problem constants (from reference)
constexpr int VOCAB = 100000;
constexpr int DIM   = 128;
constexpr int B     = 16384;
constexpr int K     = 10;
constexpr int BPB   = 8;           // batch elements per block (256 thr = 8 x 32-lane groups)
constexpr int GRID  = B / BPB;     // 2048 blocks

// Kernel 1: per-block partial sum of log-sigmoid losses -> d_ws[blockIdx.x].
// 32 lanes per batch element; each lane loads float4 (4 dims) -> 32*4 = 128 = DIM.
// No atomics, no dependency on the output buffer.
// NOTE (R2 lesson): do NOT add a min-waves arg to __launch_bounds__ — constraining
// VGPRs made the compiler serialize the 12 in-flight float4 gathers (VGPR=32,
// 118 us vs <41 us). This kernel is MLP-bound: it needs ~48+ VGPRs of loads in flight.
__global__ __launch_bounds__(256) void skipgram_partial_kernel(
    const int*   __restrict__ center_id,
    const int*   __restrict__ pos_id,
    const int*   __restrict__ neg_ids,
    const float* __restrict__ W_in,
    const float* __restrict__ W_out,
    float*       __restrict__ partial)
{
    const int tid    = threadIdx.x;
    const int lane32 = tid & 31;   // dim-group index (0..31)
    const int sub    = tid >> 5;   // batch element within block (0..7)
    const int b      = blockIdx.x * BPB + sub;

    // Issue all index loads up front -> addresses resolve in one memory round-trip.
    // neg_ids row starts at byte offset b*K*4 = b*40, which is 8-byte aligned ->
    // load the 10 indices as 5x int2.
    const int cid = center_id[b];
    const int pid = pos_id[b];
    int nid[K];
    const int2* nrow = (const int2*)(neg_ids + b * K);
#pragma unroll
    for (int k = 0; k < K / 2; ++k) {
        const int2 v = nrow[k];
        nid[2 * k]     = v.x;
        nid[2 * k + 1] = v.y;
    }

    const float4 c = ((const float4*)(W_in  + (size_t)cid * DIM))[lane32];
    const float4 p = ((const float4*)(W_out + (size_t)pid * DIM))[lane32];

    // Sum the 10 negative rows first: neg contribution is
    // log_sigmoid(-dot(center, sum_k neg_k))  (sum over k happens before sigmoid)
    float4 ns = make_float4(0.f, 0.f, 0.f, 0.f);
#pragma unroll
    for (int k = 0; k < K; ++k) {
        const float4 n = ((const float4*)(W_out + (size_t)nid[k] * DIM))[lane32];
        ns.x += n.x; ns.y += n.y; ns.z += n.z; ns.w += n.w;
    }

    float pos_partial = c.x * p.x  + c.y * p.y  + c.z * p.z  + c.w * p.w;
    float neg_partial = c.x * ns.x + c.y * ns.y + c.z * ns.z + c.w * ns.w;

    // Reduce across the 32 lanes sharing this batch element.
    // xor masks <= 16 stay within each 32-lane half of the 64-lane wave.
#pragma unroll
    for (int m = 16; m >= 1; m >>= 1) {
        pos_partial += __shfl_xor(pos_partial, m, 64);
        neg_partial += __shfl_xor(neg_partial, m, 64);
    }

    __shared__ float blocksum[BPB];
    if (lane32 == 0) {
        const float ps  = pos_partial;
        const float nsc = neg_partial;
        // stable log_sigmoid(x) = min(x,0) - log1p(exp(-|x|))
        const float lp = fminf(ps,   0.f) - log1pf(expf(-fabsf(ps)));
        const float ln = fminf(-nsc, 0.f) - log1pf(expf(-fabsf(nsc)));
        blocksum[sub] = lp + ln;
    }
    __syncthreads();

    if (tid == 0) {
        float s = 0.f;
#pragma unroll
        for (int i = 0; i < BPB; ++i) s += blocksum[i];
        partial[blockIdx.x] = s;
    }
}

// Kernel 2: reduce GRID=2048 partials -> out[0] = -(total loss).
// One block of 256 threads: 2 x float4 per thread covers 2048 floats.
__global__ __launch_bounds__(256) void skipgram_reduce_kernel(
    const float* __restrict__ partial,
    float*       __restrict__ out)
{
    const int tid = threadIdx.x;
    const float4* p4 = (const float4*)partial;   // 2048 floats = 512 float4

    float s = 0.f;
#pragma unroll
    for (int i = 0; i < 2; ++i) {
        const float4 v = p4[tid + i * 256];      // indices 0..511
        s += v.x + v.y + v.z + v.w;
    }

    // Full 64-lane wave reduction.
#pragma unroll
    for (int m = 32; m >= 1; m >>= 1) s += __shfl_xor(s, m, 64);

    __shared__ float wsum[4];
    if ((tid & 63) == 0) wsum[tid >> 6] = s;
    __syncthreads();

    if (tid == 0) out[0] = -(wsum[0] + wsum[1] + wsum[2] + wsum[3]);
}

extern "C" void kernel_launch(void* const* d_in, const int* in_sizes, int n_in,
                              void* d_out, int out_size, void* d_ws, size_t ws_size,
                              hipStream_t stream) {
    const int*   center_id = (const int*)  d_in[0];
    const int*   pos_id    = (const int*)  d_in[1];
    const int*   neg_ids   = (const int*)  d_in[2];
    const float* W_in      = (const float*)d_in[3];
    const float* W_out     = (const float*)d_in[4];
    float*       out       = (float*)d_out;
    float*       partial   = (float*)d_ws;       // 2048 floats = 8 KB of workspace

    skipgram_partial_kernel<<<GRID, 256, 0, stream>>>(
        center_id, pos_id, neg_ids, W_in, W_out, partial);
    skipgram_reduce_kernel<<<1, 256, 0, stream>>>(partial, out);
}